// Round 4
// baseline (100.659 us; speedup 1.0000x reference)
//
#include <hip/hip_runtime.h>

#define BB 4
#define NN 8192
#define BN (BB * NN)
#define ALPHA 5.0f
#define EPSF 1e-12f
#define BLOCK 256
#define QPT 4              // queries per thread (amortizes the LDS broadcast)
#define QB (BLOCK * QPT)   // 1024 queries per block
#define BIGF 1e30f

// pairs layout: pairs[s * BN + b*NN + q]   (values are d2/2, halved)
template <int NSEG>
__global__ __launch_bounds__(BLOCK, 8) void knn_kernel(
    const float* __restrict__ xyz, float2* __restrict__ pairs) {
  constexpr int SEG = NN / NSEG;
  constexpr int CHUNKS = NN / QB;
  int bid = blockIdx.x;
  int s = bid % NSEG;
  int rem = bid / NSEG;
  int qchunk = rem % CHUNKS;
  int b = rem / CHUNKS;

  const float* xb = xyz + (size_t)b * NN * 3;

  __shared__ float4 tile[SEG];
  int refBase = s * SEG;
  for (int r0 = threadIdx.x; r0 < SEG; r0 += BLOCK) {
    int r = refBase + r0;
    float px = xb[3 * r + 0], py = xb[3 * r + 1], pz = xb[3 * r + 2];
    float hpp = 0.5f * fmaf(px, px, fmaf(py, py, pz * pz));
    tile[r0] = make_float4(px, py, pz, hpp);
  }

  float nqx[QPT], nqy[QPT], nqz[QPT], hq[QPT], m1[QPT], m2[QPT];
#pragma unroll
  for (int i = 0; i < QPT; i++) {
    int q = qchunk * QB + threadIdx.x + i * BLOCK;
    float x = xb[3 * q + 0], y = xb[3 * q + 1], z = xb[3 * q + 2];
    nqx[i] = -x;
    nqy[i] = -y;
    nqz[i] = -z;
    hq[i] = 0.5f * fmaf(x, x, fmaf(y, y, z * z));
    m1[i] = BIGF;
    m2[i] = BIGF;
  }
  __syncthreads();

#pragma unroll 4
  for (int j = 0; j < SEG; j++) {
    float4 p = tile[j];
#pragma unroll
    for (int i = 0; i < QPT; i++) {
      // d2/2 = 0.5|q|^2 + 0.5|p|^2 - q.p  (4 FMA-class ops)
      float t = fmaf(nqx[i], p.x, p.w);
      t = fmaf(nqy[i], p.y, t);
      t = fmaf(nqz[i], p.z, t);
      float d = hq[i] + t;
      // 2-smallest update (2 ops): m2 = median(d, m1, m2); m1 = min
      float nm2 = __builtin_amdgcn_fmed3f(d, m1[i], m2[i]);
      m1[i] = fminf(m1[i], d);
      m2[i] = nm2;
    }
  }

#pragma unroll
  for (int i = 0; i < QPT; i++) {
    int q = qchunk * QB + threadIdx.x + i * BLOCK;
    pairs[(size_t)s * BN + b * NN + q] = make_float2(m1[i], m2[i]);
  }
}

// merge: one thread per point; un-halves, writes dsum[g] and block partials.
template <int NSEG>
__global__ __launch_bounds__(BLOCK) void merge_kernel(
    const float2* __restrict__ pairs, float* __restrict__ dsum,
    float* __restrict__ partial) {
  int g = blockIdx.x * BLOCK + threadIdx.x;  // 0 .. BN-1
  float m1 = BIGF, m2 = BIGF;
#pragma unroll 8
  for (int s = 0; s < NSEG; s++) {
    float2 p = pairs[(size_t)s * BN + g];
    float n2 = __builtin_amdgcn_fmed3f(p.x, m1, m2);
    m1 = fminf(m1, p.x);
    m2 = n2;
    n2 = __builtin_amdgcn_fmed3f(p.y, m1, m2);
    m1 = fminf(m1, p.y);
    m2 = n2;
  }
  float ds = sqrtf(fmaxf(m1 + m1, EPSF)) + sqrtf(fmaxf(m2 + m2, EPSF));
  dsum[g] = ds;

  float v = ds;
#pragma unroll
  for (int off = 32; off > 0; off >>= 1) v += __shfl_down(v, off, 64);
  __shared__ float warp_sums[BLOCK / 64];
  if ((threadIdx.x & 63) == 0) warp_sums[threadIdx.x >> 6] = v;
  __syncthreads();
  if (threadIdx.x == 0) {
    float t = 0.0f;
#pragma unroll
    for (int w = 0; w < BLOCK / 64; w++) t += warp_sums[w];
    partial[blockIdx.x] = t;
  }
}

// loss: single block of 1024 threads.
#define LBLK 1024
#define NPART (BN / BLOCK)          // 128 (merge grid size)
__global__ __launch_bounds__(LBLK) void loss_kernel(
    const float* __restrict__ dsum, const float* __restrict__ partial,
    float* __restrict__ out) {
  __shared__ float s_avg[BB];
  if (threadIdx.x < NPART) {
    float v = partial[threadIdx.x];
#pragma unroll
    for (int off = 16; off > 0; off >>= 1) v += __shfl_down(v, off, 32);
    if ((threadIdx.x & 31) == 0) s_avg[threadIdx.x >> 5] = v * (ALPHA / NN);
  }
  __syncthreads();

  const float4* d4 = (const float4*)dsum;
  float acc = 0.0f;
#pragma unroll
  for (int it = 0; it < BN / (LBLK * 4); it++) {
    int idx = it * LBLK + threadIdx.x;     // float4 index
    float4 v = d4[idx];
    float thr = s_avg[idx >> 11];          // 2048 float4 per batch
    acc += (v.x > thr) ? v.x : 0.0f;
    acc += (v.y > thr) ? v.y : 0.0f;
    acc += (v.z > thr) ? v.z : 0.0f;
    acc += (v.w > thr) ? v.w : 0.0f;
  }
#pragma unroll
  for (int off = 32; off > 0; off >>= 1) acc += __shfl_down(acc, off, 64);
  __shared__ float warp_sums[LBLK / 64];
  if ((threadIdx.x & 63) == 0) warp_sums[threadIdx.x >> 6] = acc;
  __syncthreads();
  if (threadIdx.x == 0) {
    float t = 0.0f;
#pragma unroll
    for (int w = 0; w < LBLK / 64; w++) t += warp_sums[w];
    out[0] = t;
  }
}

template <int NSEG>
static void run(const float* xyz, float* out, void* d_ws, hipStream_t stream) {
  float2* pairs = (float2*)d_ws;
  float* dsum = (float*)(pairs + (size_t)NSEG * BN);
  float* partial = dsum + BN;
  int grid1 = BB * (NN / QB) * NSEG;
  knn_kernel<NSEG><<<grid1, BLOCK, 0, stream>>>(xyz, pairs);
  merge_kernel<NSEG><<<BN / BLOCK, BLOCK, 0, stream>>>(pairs, dsum, partial);
  loss_kernel<<<1, LBLK, 0, stream>>>(dsum, partial, out);
}

extern "C" void kernel_launch(void* const* d_in, const int* in_sizes, int n_in,
                              void* d_out, int out_size, void* d_ws,
                              size_t ws_size, hipStream_t stream) {
  const float* xyz = (const float*)d_in[0];
  float* out = (float*)d_out;

  auto need = [](int nseg) {
    return (size_t)nseg * BN * sizeof(float2) + BN * sizeof(float) +
           NPART * sizeof(float);
  };
  if (ws_size >= need(64)) {
    run<64>(xyz, out, d_ws, stream);   // grid1 = 2048 blocks, 8/CU
  } else if (ws_size >= need(32)) {
    run<32>(xyz, out, d_ws, stream);
  } else {
    run<16>(xyz, out, d_ws, stream);
  }
}

// Round 5
// 98.858 us; speedup vs baseline: 1.0182x; 1.0182x over previous
//
#include <hip/hip_runtime.h>

#define BB 4
#define NN 8192
#define BN (BB * NN)
#define ALPHA 5.0f
#define EPSF 1e-12f
#define BLOCK 256
#define QPT 4              // queries per thread
#define QB (BLOCK * QPT)   // 1024 queries per block
#define BIGF 1e30f

// prep: refs4[g] = (x, y, z, 0.5*||p||^2)
__global__ __launch_bounds__(BLOCK) void prep_kernel(
    const float* __restrict__ xyz, float4* __restrict__ refs4) {
  int g = blockIdx.x * BLOCK + threadIdx.x;  // 0..BN-1
  float x = xyz[3 * g + 0], y = xyz[3 * g + 1], z = xyz[3 * g + 2];
  float hpp = 0.5f * fmaf(x, x, fmaf(y, y, z * z));
  refs4[g] = make_float4(x, y, z, hpp);
}

// pairs layout: pairs[s * BN + b*NN + q]   (values are d2/2)
template <int NSEG>
__global__ __launch_bounds__(BLOCK, 8) void knn_kernel(
    const float4* __restrict__ refs4, float2* __restrict__ pairs) {
  constexpr int SEG = NN / NSEG;
  constexpr int CHUNKS = NN / QB;
  int bid = blockIdx.x;
  int s = bid % NSEG;
  int rem = bid / NSEG;
  int qchunk = rem % CHUNKS;
  int b = rem / CHUNKS;

  const float4* __restrict__ qb4 = refs4 + (size_t)b * NN;

  float nqx[QPT], nqy[QPT], nqz[QPT], hq[QPT], m1[QPT], m2[QPT];
#pragma unroll
  for (int i = 0; i < QPT; i++) {
    int q = qchunk * QB + threadIdx.x + i * BLOCK;
    float4 qp = qb4[q];                    // coalesced vector load
    nqx[i] = -qp.x;
    nqy[i] = -qp.y;
    nqz[i] = -qp.z;
    hq[i] = qp.w;
    m1[i] = BIGF;
    m2[i] = BIGF;
  }

  // wave-uniform ref stream -> scalar loads (s_load_dwordx4), no LDS.
  const float4* __restrict__ rp = qb4 + s * SEG;
#pragma unroll 4
  for (int j = 0; j < SEG; j++) {
    float4 p = rp[j];
    float pw = p.w;  // one v_mov per j; keeps each fma to a single SGPR src
#pragma unroll
    for (int i = 0; i < QPT; i++) {
      // key = 0.5||p||^2 - q.p   (selection key, shifted by -hq per query)
      float t = fmaf(nqx[i], p.x, pw);
      t = fmaf(nqy[i], p.y, t);
      t = fmaf(nqz[i], p.z, t);
      m2[i] = __builtin_amdgcn_fmed3f(t, m1[i], m2[i]);  // uses old m1
      m1[i] = fminf(m1[i], t);
    }
  }

#pragma unroll
  for (int i = 0; i < QPT; i++) {
    int q = qchunk * QB + threadIdx.x + i * BLOCK;
    pairs[(size_t)s * BN + b * NN + q] =
        make_float2(m1[i] + hq[i], m2[i] + hq[i]);  // un-shift -> d2/2
  }
}

// merge: one thread per point; 256 blocks x 128 threads.
#define MBLK 128
#define NPART (BN / MBLK)  // 256
template <int NSEG>
__global__ __launch_bounds__(MBLK) void merge_kernel(
    const float2* __restrict__ pairs, float* __restrict__ dsum,
    float* __restrict__ partial) {
  int g = blockIdx.x * MBLK + threadIdx.x;  // 0 .. BN-1
  float m1 = BIGF, m2 = BIGF;
#pragma unroll 8
  for (int s = 0; s < NSEG; s++) {
    float2 p = pairs[(size_t)s * BN + g];
    float n2 = __builtin_amdgcn_fmed3f(p.x, m1, m2);
    m1 = fminf(m1, p.x);
    m2 = n2;
    n2 = __builtin_amdgcn_fmed3f(p.y, m1, m2);
    m1 = fminf(m1, p.y);
    m2 = n2;
  }
  float ds = sqrtf(fmaxf(m1 + m1, EPSF)) + sqrtf(fmaxf(m2 + m2, EPSF));
  dsum[g] = ds;

  float v = ds;
#pragma unroll
  for (int off = 32; off > 0; off >>= 1) v += __shfl_down(v, off, 64);
  __shared__ float warp_sums[MBLK / 64];
  if ((threadIdx.x & 63) == 0) warp_sums[threadIdx.x >> 6] = v;
  __syncthreads();
  if (threadIdx.x == 0) {
    float t = 0.0f;
#pragma unroll
    for (int w = 0; w < MBLK / 64; w++) t += warp_sums[w];
    partial[blockIdx.x] = t;
  }
}

// loss: single block of 1024 threads.
#define LBLK 1024
#define PPB (NPART / BB)  // 64 partials per batch
__global__ __launch_bounds__(LBLK) void loss_kernel(
    const float* __restrict__ dsum, const float* __restrict__ partial,
    float* __restrict__ out) {
  __shared__ float s_avg[BB];
  if (threadIdx.x < NPART) {
    float v = partial[threadIdx.x];  // 64 consecutive partials per batch
#pragma unroll
    for (int off = 32; off > 0; off >>= 1) v += __shfl_down(v, off, 64);
    if ((threadIdx.x & 63) == 0) s_avg[threadIdx.x >> 6] = v * (ALPHA / NN);
  }
  __syncthreads();

  const float4* d4 = (const float4*)dsum;
  float acc = 0.0f;
#pragma unroll
  for (int it = 0; it < BN / (LBLK * 4); it++) {
    int idx = it * LBLK + threadIdx.x;  // float4 index
    float4 v = d4[idx];
    float thr = s_avg[idx >> 11];       // 2048 float4 per batch
    acc += (v.x > thr) ? v.x : 0.0f;
    acc += (v.y > thr) ? v.y : 0.0f;
    acc += (v.z > thr) ? v.z : 0.0f;
    acc += (v.w > thr) ? v.w : 0.0f;
  }
#pragma unroll
  for (int off = 32; off > 0; off >>= 1) acc += __shfl_down(acc, off, 64);
  __shared__ float warp_sums[LBLK / 64];
  if ((threadIdx.x & 63) == 0) warp_sums[threadIdx.x >> 6] = acc;
  __syncthreads();
  if (threadIdx.x == 0) {
    float t = 0.0f;
#pragma unroll
    for (int w = 0; w < LBLK / 64; w++) t += warp_sums[w];
    out[0] = t;
  }
}

template <int NSEG>
static void run(const float* xyz, float* out, void* d_ws, hipStream_t stream) {
  float2* pairs = (float2*)d_ws;
  float4* refs4 = (float4*)(pairs + (size_t)NSEG * BN);
  float* dsum = (float*)(refs4 + BN);
  float* partial = dsum + BN;
  prep_kernel<<<BN / BLOCK, BLOCK, 0, stream>>>(xyz, refs4);
  int grid1 = BB * (NN / QB) * NSEG;
  knn_kernel<NSEG><<<grid1, BLOCK, 0, stream>>>(refs4, pairs);
  merge_kernel<NSEG><<<BN / MBLK, MBLK, 0, stream>>>(pairs, dsum, partial);
  loss_kernel<<<1, LBLK, 0, stream>>>(dsum, partial, out);
}

extern "C" void kernel_launch(void* const* d_in, const int* in_sizes, int n_in,
                              void* d_out, int out_size, void* d_ws,
                              size_t ws_size, hipStream_t stream) {
  const float* xyz = (const float*)d_in[0];
  float* out = (float*)d_out;

  auto need = [](int nseg) {
    return (size_t)nseg * BN * sizeof(float2) + BN * sizeof(float4) +
           BN * sizeof(float) + NPART * sizeof(float);
  };
  if (ws_size >= need(32)) {
    run<32>(xyz, out, d_ws, stream);  // grid1 = 1024 blocks, 4/CU
  } else if (ws_size >= need(16)) {
    run<16>(xyz, out, d_ws, stream);
  } else {
    run<8>(xyz, out, d_ws, stream);
  }
}

// Round 6
// 97.552 us; speedup vs baseline: 1.0318x; 1.0134x over previous
//
#include <hip/hip_runtime.h>

#define BB 4
#define NN 8192
#define BN (BB * NN)
#define ALPHA 5.0f
#define EPSF 1e-12f
#define BLOCK 256
#define QPT 4              // queries per thread
#define QB (BLOCK * QPT)   // 1024 queries per block
#define BIGF 1e30f

// prep: refs4[g] = (x, y, z, 0.5*||p||^2)
__global__ __launch_bounds__(BLOCK) void prep_kernel(
    const float* __restrict__ xyz, float4* __restrict__ refs4) {
  int g = blockIdx.x * BLOCK + threadIdx.x;  // 0..BN-1
  float x = xyz[3 * g + 0], y = xyz[3 * g + 1], z = xyz[3 * g + 2];
  float hpp = 0.5f * fmaf(x, x, fmaf(y, y, z * z));
  refs4[g] = make_float4(x, y, z, hpp);
}

// pairs layout: pairs[s * BN + b*NN + q]   (values are d2/2)
template <int NSEG>
__global__ __launch_bounds__(BLOCK, 8) void knn_kernel(
    const float4* __restrict__ refs4, float2* __restrict__ pairs) {
  constexpr int SEG = NN / NSEG;
  constexpr int CHUNKS = NN / QB;
  constexpr int U = 8;  // refs per pipeline stage (2x s_load_dwordx16)
  int bid = blockIdx.x;
  int s = bid % NSEG;
  int rem = bid / NSEG;
  int qchunk = rem % CHUNKS;
  int b = rem / CHUNKS;

  const float4* __restrict__ qb4 = refs4 + (size_t)b * NN;

  float nqx[QPT], nqy[QPT], nqz[QPT], hq[QPT], m1[QPT], m2[QPT];
#pragma unroll
  for (int i = 0; i < QPT; i++) {
    int q = qchunk * QB + threadIdx.x + i * BLOCK;
    float4 qp = qb4[q];  // coalesced vector load
    nqx[i] = -qp.x;
    nqy[i] = -qp.y;
    nqz[i] = -qp.z;
    hq[i] = qp.w;
    m1[i] = BIGF;
    m2[i] = BIGF;
  }

  // wave-uniform ref stream -> scalar loads, software-pipelined double buffer.
  const float4* __restrict__ rp = qb4 + s * SEG;
  float4 cur[U];
#pragma unroll
  for (int u = 0; u < U; u++) cur[u] = rp[u];

  for (int j0 = 0; j0 < SEG; j0 += U) {
    // issue next group's loads before using cur (wrap on last iter; harmless)
    int jn = (j0 + U < SEG) ? (j0 + U) : 0;
    float4 nxt[U];
#pragma unroll
    for (int u = 0; u < U; u++) nxt[u] = rp[jn + u];

#pragma unroll
    for (int u = 0; u < U; u++) {
      float4 p = cur[u];
      float pw = p.w;  // force VGPR copy: keeps each fma to 1 SGPR operand
#pragma unroll
      for (int i = 0; i < QPT; i++) {
        // key = 0.5||p||^2 - q.p  (per-query shift by -hq preserves order)
        float t = fmaf(nqx[i], p.x, pw);
        t = fmaf(nqy[i], p.y, t);
        t = fmaf(nqz[i], p.z, t);
        m2[i] = __builtin_amdgcn_fmed3f(t, m1[i], m2[i]);  // uses old m1
        m1[i] = fminf(m1[i], t);
      }
    }
#pragma unroll
    for (int u = 0; u < U; u++) cur[u] = nxt[u];
  }

#pragma unroll
  for (int i = 0; i < QPT; i++) {
    int q = qchunk * QB + threadIdx.x + i * BLOCK;
    pairs[(size_t)s * BN + b * NN + q] =
        make_float2(m1[i] + hq[i], m2[i] + hq[i]);  // un-shift -> d2/2
  }
}

// merge: one thread per point; 256 blocks x 128 threads.
#define MBLK 128
#define NPART (BN / MBLK)  // 256
template <int NSEG>
__global__ __launch_bounds__(MBLK) void merge_kernel(
    const float2* __restrict__ pairs, float* __restrict__ dsum,
    float* __restrict__ partial) {
  int g = blockIdx.x * MBLK + threadIdx.x;  // 0 .. BN-1
  float m1 = BIGF, m2 = BIGF;
#pragma unroll 8
  for (int s = 0; s < NSEG; s++) {
    float2 p = pairs[(size_t)s * BN + g];
    float n2 = __builtin_amdgcn_fmed3f(p.x, m1, m2);
    m1 = fminf(m1, p.x);
    m2 = n2;
    n2 = __builtin_amdgcn_fmed3f(p.y, m1, m2);
    m1 = fminf(m1, p.y);
    m2 = n2;
  }
  float ds = sqrtf(fmaxf(m1 + m1, EPSF)) + sqrtf(fmaxf(m2 + m2, EPSF));
  dsum[g] = ds;

  float v = ds;
#pragma unroll
  for (int off = 32; off > 0; off >>= 1) v += __shfl_down(v, off, 64);
  __shared__ float warp_sums[MBLK / 64];
  if ((threadIdx.x & 63) == 0) warp_sums[threadIdx.x >> 6] = v;
  __syncthreads();
  if (threadIdx.x == 0) {
    float t = 0.0f;
#pragma unroll
    for (int w = 0; w < MBLK / 64; w++) t += warp_sums[w];
    partial[blockIdx.x] = t;
  }
}

// loss: single block of 1024 threads.
#define LBLK 1024
__global__ __launch_bounds__(LBLK) void loss_kernel(
    const float* __restrict__ dsum, const float* __restrict__ partial,
    float* __restrict__ out) {
  __shared__ float s_avg[BB];
  if (threadIdx.x < NPART) {
    float v = partial[threadIdx.x];  // 64 consecutive partials per batch
#pragma unroll
    for (int off = 32; off > 0; off >>= 1) v += __shfl_down(v, off, 64);
    if ((threadIdx.x & 63) == 0) s_avg[threadIdx.x >> 6] = v * (ALPHA / NN);
  }
  __syncthreads();

  const float4* d4 = (const float4*)dsum;
  float acc = 0.0f;
#pragma unroll
  for (int it = 0; it < BN / (LBLK * 4); it++) {
    int idx = it * LBLK + threadIdx.x;  // float4 index
    float4 v = d4[idx];
    float thr = s_avg[idx >> 11];       // 2048 float4 per batch
    acc += (v.x > thr) ? v.x : 0.0f;
    acc += (v.y > thr) ? v.y : 0.0f;
    acc += (v.z > thr) ? v.z : 0.0f;
    acc += (v.w > thr) ? v.w : 0.0f;
  }
#pragma unroll
  for (int off = 32; off > 0; off >>= 1) acc += __shfl_down(acc, off, 64);
  __shared__ float warp_sums[LBLK / 64];
  if ((threadIdx.x & 63) == 0) warp_sums[threadIdx.x >> 6] = acc;
  __syncthreads();
  if (threadIdx.x == 0) {
    float t = 0.0f;
#pragma unroll
    for (int w = 0; w < LBLK / 64; w++) t += warp_sums[w];
    out[0] = t;
  }
}

template <int NSEG>
static void run(const float* xyz, float* out, void* d_ws, hipStream_t stream) {
  float2* pairs = (float2*)d_ws;
  float4* refs4 = (float4*)(pairs + (size_t)NSEG * BN);
  float* dsum = (float*)(refs4 + BN);
  float* partial = dsum + BN;
  prep_kernel<<<BN / BLOCK, BLOCK, 0, stream>>>(xyz, refs4);
  int grid1 = BB * (NN / QB) * NSEG;
  knn_kernel<NSEG><<<grid1, BLOCK, 0, stream>>>(refs4, pairs);
  merge_kernel<NSEG><<<BN / MBLK, MBLK, 0, stream>>>(pairs, dsum, partial);
  loss_kernel<<<1, LBLK, 0, stream>>>(dsum, partial, out);
}

extern "C" void kernel_launch(void* const* d_in, const int* in_sizes, int n_in,
                              void* d_out, int out_size, void* d_ws,
                              size_t ws_size, hipStream_t stream) {
  const float* xyz = (const float*)d_in[0];
  float* out = (float*)d_out;

  auto need = [](int nseg) {
    return (size_t)nseg * BN * sizeof(float2) + BN * sizeof(float4) +
           BN * sizeof(float) + NPART * sizeof(float);
  };
  if (ws_size >= need(64)) {
    run<64>(xyz, out, d_ws, stream);  // grid1 = 2048 blocks, 8/CU
  } else if (ws_size >= need(32)) {
    run<32>(xyz, out, d_ws, stream);
  } else {
    run<16>(xyz, out, d_ws, stream);
  }
}